// Round 7
// baseline (951.429 us; speedup 1.0000x reference)
//
#include <hip/hip_runtime.h>
#include <stdint.h>

// Problem constants
#define BB   8
#define NH   8
#define QQ   100
#define HWK  16384
#define DM   256
#define HD   32
#define QP   112      // Q padded to 7 * 16
#define MT   7        // m-tiles of 16 rows
#define NPART 64      // key partials per (b,h): 16 chunks * 4 waves
// 1/sqrt(32) * log2(e)  (exp(x) == exp2(x*log2e), folded into q-scale)
#define SCALE2 0.2550602534365564f

// R7 DIAGNOSTIC (narrow): ONLY kv_kernel and attn_kernel grids are doubled
// via modulo block map (second half redoes the first half, byte-identical
// idempotent writes -> output unchanged). Purpose: total - 815us = kv+attn
// true cost, and any kernel with 2x dur > ~256us surfaces in rocprof top-5
// with full counters. qw/combine are byte-identical to R6.

typedef short bf16x8 __attribute__((ext_vector_type(8)));
typedef float f32x4  __attribute__((ext_vector_type(4)));
typedef unsigned short u16;
typedef unsigned int   u32;
typedef unsigned long long u64;

__device__ __forceinline__ u16 f2bf(float f) {          // RNE
  u32 u = __builtin_bit_cast(u32, f);
  u += 0x7fffu + ((u >> 16) & 1u);
  return (u16)(u >> 16);
}
__device__ __forceinline__ u16 f2bf_ru(float f) {       // round-half-up (2 VALU)
  return (u16)((__builtin_bit_cast(u32, f) + 0x8000u) >> 16);
}
// pack two fp32 -> bf16x2 (round-half-up), 3 VALU via v_perm
__device__ __forceinline__ u32 pack2rn(float lo, float hi) {
  u32 a = __builtin_bit_cast(u32, lo) + 0x8000u;
  u32 b = __builtin_bit_cast(u32, hi) + 0x8000u;
  return __builtin_amdgcn_perm(b, a, 0x07060302u);
}
__device__ __forceinline__ float bf_lo(u32 u) {
  return __builtin_bit_cast(float, u << 16);
}
__device__ __forceinline__ float bf_hi(u32 u) {
  return __builtin_bit_cast(float, u & 0xffff0000u);
}
__device__ __forceinline__ float fast_exp2(float x) {
#if __has_builtin(__builtin_amdgcn_exp2f)
  return __builtin_amdgcn_exp2f(x);
#else
  return exp2f(x);
#endif
}

// ---------------------------------------------------------------------------
// Kernel 1: mask ballot-compression (1024 blocks) + q projection (800) +
// wconv (128). (Unchanged from R6.)
// ---------------------------------------------------------------------------
__global__ __launch_bounds__(256) void qw_kernel(
    const float* __restrict__ query, const float* __restrict__ W,
    const float* __restrict__ bias, const int* __restrict__ mask,
    u16* __restrict__ q_bf, u16* __restrict__ wbf, u32* __restrict__ mbg) {
  __shared__ float xrow[DM];
  const int bid = blockIdx.x;
  const int tid = threadIdx.x, lane = tid & 63, wid = tid >> 6;

  if (bid < 1024) {                           // ---- mask compress ----
    const int cpid = bid;                     // bh*16 + chunk
    const int bh = cpid >> 4, chunk = cpid & 15;
    const int* mp_base = mask + (size_t)bh * QQ * HWK + chunk * 1024;
    u32* dst_base = mbg + (size_t)cpid * QP * 32;
    for (int rr = 0; rr < 25; ++rr) {
      const int row = wid * 25 + rr;
      const int* mp = mp_base + (size_t)row * HWK;
      int4 v[4];
      #pragma unroll
      for (int q = 0; q < 4; ++q) v[q] = ((const int4*)(mp + q * 256))[lane];
      #pragma unroll
      for (int q = 0; q < 4; ++q) {
        const u64 b0 = __ballot(v[q].x != 0);
        const u64 b1 = __ballot(v[q].y != 0);
        const u64 b2 = __ballot(v[q].z != 0);
        const u64 b3 = __ballot(v[q].w != 0);
        if (lane < 8) {
          const int j = lane >> 1;
          const u64 bj = (j == 0) ? b0 : (j == 1) ? b1 : (j == 2) ? b2 : b3;
          dst_base[row * 32 + q * 8 + (lane & 1) * 4 + j] =
              (lane & 1) ? (u32)(bj >> 32) : (u32)bj;
        }
      }
    }
    return;
  }
  if (bid >= 1024 + BB * QQ) {                // ---- wconv ----
    const int i = ((bid - 1024 - BB * QQ) * 256 + tid) * 4;  // 131072 elems
    const float4 w = *(const float4*)(W + 256 * DM + i);
    u32* dst = (u32*)(wbf + i);
    dst[0] = pack2rn(w.x, w.y);
    dst[1] = pack2rn(w.z, w.w);
    return;
  }
  // ---- q projection ----
  const int bq = bid - 1024;
  const int b = bq / QQ, qi = bq % QQ;
  if (tid < 64)
    ((float4*)xrow)[tid] = ((const float4*)(query + (size_t)bq * DM))[tid];
  __syncthreads();
  const int j = tid;
  float acc = bias[j];
  const float4* wr = (const float4*)(W + (size_t)j * DM);
  #pragma unroll 8
  for (int c = 0; c < 64; ++c) {
    float4 w = wr[c];
    float4 x = ((const float4*)xrow)[c];
    acc += w.x * x.x + w.y * x.y + w.z * x.z + w.w * x.w;
  }
  acc *= SCALE2;
  const int h = j >> 5, d = j & 31;
  q_bf[(((size_t)(b * NH + h)) * QQ + qi) * HD + d] = f2bf(acc);
}

// ---------------------------------------------------------------------------
// Kernel 2: K/V projection GEMM (R6 structure). DIAGNOSTIC: grid 4096,
// blocks >= 2048 redo blocks 0..2047 (idempotent).
// ---------------------------------------------------------------------------
__global__ __launch_bounds__(512, 4) void kv_kernel(
    const float* __restrict__ kv, const u16* __restrict__ wbf,
    const float* __restrict__ bias, u16* __restrict__ k_bf,
    u16* __restrict__ v_t) {
  __shared__ u16 S[19456];   // A [64][264] (16896 u16)  ∪  T: 4*2304 + 4*2560
  int rb = blockIdx.x;
  if (rb >= 2048) rb -= 2048;                // diagnostic doubling
  const size_t m0 = (size_t)rb * 64;
  const int tid = threadIdx.x, lane = tid & 63, wid = tid >> 6;
  const int lane15 = lane & 15, quad = lane >> 4;
  const int jw = wid * 64;                   // col base within 512

  // ---- stage A (64 rows x 256 cols of kv) to LDS bf16, row stride 264 ----
  #pragma unroll
  for (int t = 0; t < 8; ++t) {
    const int idx = t * 512 + tid;           // float4 index, 4096 total
    const int row = idx >> 6, c4 = idx & 63;
    const float4 a = *(const float4*)(kv + (m0 + row) * DM + c4 * 4);
    u32* dst = (u32*)&S[row * 264 + c4 * 4];
    dst[0] = pack2rn(a.x, a.y);
    dst[1] = pack2rn(a.z, a.w);
  }
  __syncthreads();

  f32x4 acc[4][4];
  #pragma unroll
  for (int mi = 0; mi < 4; ++mi)
    #pragma unroll
    for (int ni = 0; ni < 4; ++ni) acc[mi][ni] = (f32x4){0.f, 0.f, 0.f, 0.f};

  for (int ks = 0; ks < 8; ++ks) {
    bf16x8 afr[4];
    #pragma unroll
    for (int mi = 0; mi < 4; ++mi)
      afr[mi] = __builtin_bit_cast(bf16x8,
          *(const uint4*)&S[(mi * 16 + lane15) * 264 + ks * 32 + quad * 8]);
    #pragma unroll
    for (int ni = 0; ni < 4; ++ni) {
      bf16x8 bfr = __builtin_bit_cast(bf16x8,
          *(const uint4*)(wbf + (size_t)(jw + ni * 16 + lane15) * DM + ks * 32 + quad * 8));
      #pragma unroll
      for (int mi = 0; mi < 4; ++mi)
        acc[mi][ni] = __builtin_amdgcn_mfma_f32_16x16x32_bf16(afr[mi], bfr, acc[mi][ni], 0, 0, 0);
    }
  }
  __syncthreads();   // all waves done reading A before T overwrites it

  const float* bptr = bias + 256 + jw;
  if (wid < 4) {
    u16* T = S + wid * 2304;                  // [32][72]
    #pragma unroll
    for (int p = 0; p < 2; ++p) {
      #pragma unroll
      for (int mm = 0; mm < 2; ++mm) {
        const int mi = p * 2 + mm;
        #pragma unroll
        for (int ni = 0; ni < 4; ++ni) {
          const float bv = bptr[ni * 16 + lane15];
          #pragma unroll
          for (int r = 0; r < 4; ++r)
            T[(mm * 16 + quad * 4 + r) * 72 + ni * 16 + lane15] =
                f2bf_ru(acc[mi][ni][r] + bv);
        }
      }
      #pragma unroll
      for (int it = 0; it < 8; ++it) {
        const int row = it * 4 + quad;          // 0..31
        const int c0 = lane15 * 4;              // 0..60
        uint2 val = *(const uint2*)&T[row * 72 + c0];
        const size_t m = m0 + p * 32 + row;
        const size_t b = m >> 14, key = m & 16383;
        const int col256 = jw + c0;             // 0..255 within K
        const int h = col256 >> 5, d = col256 & 31;
        *(uint2*)&k_bf[((b * NH + h) * HWK + key) * HD + d] = val;
      }
    }
  } else {
    u16* T = S + 9216 + (wid - 4) * 2560;     // [64][40]
    const int jwv = jw - 256;                  // 0..192 within V
    #pragma unroll
    for (int p = 0; p < 2; ++p) {
      #pragma unroll
      for (int mm = 0; mm < 2; ++mm) {
        const int mi = p * 2 + mm;
        #pragma unroll
        for (int ni = 0; ni < 4; ++ni) {
          const float bv = bptr[ni * 16 + lane15];
          u32* dst = (u32*)&T[(ni * 16 + lane15) * 40 + mm * 16 + quad * 4];
          dst[0] = pack2rn(acc[mi][ni][0] + bv, acc[mi][ni][1] + bv);
          dst[1] = pack2rn(acc[mi][ni][2] + bv, acc[mi][ni][3] + bv);
        }
      }
      #pragma unroll
      for (int it = 0; it < 4; ++it) {
        const int col = it * 16 + (lane >> 2);  // 0..63
        const int koff = (lane & 3) * 8;        // 0..24
        uint4 val = *(const uint4*)&T[col * 40 + koff];
        const size_t m = m0 + p * 32 + koff;
        const size_t b = m >> 14, key = m & 16383;
        const int col256 = jwv + col;           // 0..255 within V
        const int h = col256 >> 5, d = col256 & 31;
        *(uint4*)&v_t[((b * NH + h) * HD + d) * HWK + key] = val;
      }
    }
  }
}

// ---------------------------------------------------------------------------
// Kernel 3: attention, shuffle-free P path (R6 structure). DIAGNOSTIC:
// grid 2048, blocks >= 1024 redo blocks 0..1023 (idempotent).
// ---------------------------------------------------------------------------
__global__ __launch_bounds__(256) void attn_kernel(
    const u16* __restrict__ q_bf, const u16* __restrict__ k_bf,
    const u16* __restrict__ v_t, const u32* __restrict__ mbg,
    float* __restrict__ l_p, u32* __restrict__ ctxp) {
  const int tid = threadIdx.x;
  const int lane = tid & 63, wid = tid >> 6;
  const int lane15 = lane & 15, quad = lane >> 4;
  const int bidx = blockIdx.x & 1023;         // diagnostic doubling
  const int bh = bidx >> 4, chunk = bidx & 15;

  const int key_base = chunk * 1024 + wid * 256;
  const u16* kbase = k_bf + (size_t)bh * HWK * HD;
  const u16* vtb  = v_t  + (size_t)bh * HWK * HD;
  const u16* qb   = q_bf + (size_t)bh * QQ * HD;
  const u32* mrow = mbg + (size_t)bidx * QP * 32 + wid * 8;

  // permuted key offset for this lane's A-rows: row l15 <- key kp (kf0), kp+4 (kf1)
  const int kp = 8 * (lane15 >> 2) + (lane15 & 3);

  f32x4 acc[MT][2];
  float l_run[MT];
  #pragma unroll
  for (int mt = 0; mt < MT; ++mt) {
    acc[mt][0] = (f32x4){0.f, 0.f, 0.f, 0.f};
    acc[mt][1] = (f32x4){0.f, 0.f, 0.f, 0.f};
    l_run[mt] = 0.f;
  }

  for (int kg = 0; kg < 8; ++kg) {
    const int key0 = key_base + kg * 32;
    const int h4 = (kg & 4) ? 4 : 0;
    const int sh = ((kg & 3) << 3) + 2 * quad;        // bit base for this kg
    bf16x8 kf0 = __builtin_bit_cast(bf16x8,
        *(const uint4*)(kbase + (size_t)(key0 + kp) * HD + quad * 8));
    bf16x8 kf1 = __builtin_bit_cast(bf16x8,
        *(const uint4*)(kbase + (size_t)(key0 + kp + 4) * HD + quad * 8));
    bf16x8 vf0 = __builtin_bit_cast(bf16x8,
        *(const uint4*)(vtb + (size_t)lane15 * HWK + key0 + quad * 8));
    bf16x8 vf1 = __builtin_bit_cast(bf16x8,
        *(const uint4*)(vtb + (size_t)(lane15 + 16) * HWK + key0 + quad * 8));
    #pragma unroll
    for (int mt = 0; mt < MT; ++mt) {
      const int rowg = mt * 16 + lane15;              // this lane's q-row
      bf16x8 af = __builtin_bit_cast(bf16x8,
          *(const uint4*)(qb + (size_t)rowg * HD + quad * 8));
      uint4 mwv = *(const uint4*)(mrow + rowg * 32 + h4); // words j=0..3
      if (mt == MT - 1 && rowg >= QQ) mwv = (uint4){0u, 0u, 0u, 0u};
      const f32x4 zero = {0.f, 0.f, 0.f, 0.f};
      // S^T: lane (q,l15) rows 4q+r -> keys key0 + {8q+r (s0), 8q+4+r (s1)}
      f32x4 s0 = __builtin_amdgcn_mfma_f32_16x16x32_bf16(kf0, af, zero, 0, 0, 0);
      f32x4 s1 = __builtin_amdgcn_mfma_f32_16x16x32_bf16(kf1, af, zero, 0, 0, 0);
      const u32 mw[4] = {mwv.x, mwv.y, mwv.z, mwv.w};
      float p0[4], p1[4];
      float lsum = 0.f;
      #pragma unroll
      for (int r = 0; r < 4; ++r) {
        // key 8q+r   -> word r, bit sh; key 8q+4+r -> word r, bit sh+1
        p0[r] = ((mw[r] >> sh) & 1u)       ? fast_exp2(s0[r]) : 0.f;
        p1[r] = ((mw[r] >> (sh + 1)) & 1u) ? fast_exp2(s1[r]) : 0.f;
        lsum += p0[r] + p1[r];
      }
      l_run[mt] += lsum;
      // PV B-fragment: elems j=0..7 = P[key 8q+j] = {p0[0..3], p1[0..3]}
      uint4 pw;
      pw.x = pack2rn(p0[0], p0[1]);
      pw.y = pack2rn(p0[2], p0[3]);
      pw.z = pack2rn(p1[0], p1[1]);
      pw.w = pack2rn(p1[2], p1[3]);
      bf16x8 pf = __builtin_bit_cast(bf16x8, pw);
      // ctx^T: m=dim, n=qrow
      acc[mt][0] = __builtin_amdgcn_mfma_f32_16x16x32_bf16(vf0, pf, acc[mt][0], 0, 0, 0);
      acc[mt][1] = __builtin_amdgcn_mfma_f32_16x16x32_bf16(vf1, pf, acc[mt][1], 0, 0, 0);
    }
  }

  const int part = chunk * 4 + wid;
  #pragma unroll
  for (int mt = 0; mt < MT; ++mt) {
    const int row = mt * 16 + lane15;               // qrow (rows >= 100 junk, never read)
    float lr = l_run[mt];
    lr += __shfl_xor(lr, 16);
    lr += __shfl_xor(lr, 32);
    const size_t base = ((size_t)bh * QP + row) * NPART + part;
    if (quad == 0) l_p[base] = lr;
    // ctx^T: lane holds dims quad*4+r (acc0) and 16+quad*4+r (acc1), qrow=lane15
    uint2 lo2, hi2;
    lo2.x = pack2rn(acc[mt][0][0], acc[mt][0][1]);
    lo2.y = pack2rn(acc[mt][0][2], acc[mt][0][3]);
    hi2.x = pack2rn(acc[mt][1][0], acc[mt][1][1]);
    hi2.y = pack2rn(acc[mt][1][2], acc[mt][1][3]);
    *(uint2*)&ctxp[base * 16 + quad * 2]     = lo2;  // dims 4q..4q+3
    *(uint2*)&ctxp[base * 16 + 8 + quad * 2] = hi2;  // dims 16+4q..16+4q+3
  }
}

// ---------------------------------------------------------------------------
// Kernel 4: combine partials (bf16-packed ctx) + out-proj + residual + LN.
// (Unchanged from R6.)
// ---------------------------------------------------------------------------
__global__ __launch_bounds__(256) void combine_kernel(
    const float* __restrict__ l_p, const u32* __restrict__ ctxp,
    const float* __restrict__ query, const float* __restrict__ Wo,
    const float* __restrict__ bo, const float* __restrict__ lnw,
    const float* __restrict__ lnb, float* __restrict__ out) {
  __shared__ float ctx_row[DM];
  __shared__ float red[8];
  const int bq = blockIdx.x;
  const int b = bq / QQ, qi = bq % QQ;
  const int tid = threadIdx.x, lane = tid & 63, wid = tid >> 6;

  for (int hh = 0; hh < 2; ++hh) {
    const int h = wid * 2 + hh;
    const size_t base = ((size_t)(b * NH + h) * QP + qi) * NPART;
    float lv = l_p[base + lane];
    #pragma unroll
    for (int o = 1; o < 64; o <<= 1) lv += __shfl_xor(lv, o);
    const float inv_l = 1.0f / lv;
    // lane = (part group pg, u32-pair c): dims 4c..4c+3
    const int c = lane & 7, pg = lane >> 3;
    const u32* cp = ctxp + base * 16 + c * 2;
    float s0 = 0.f, s1 = 0.f, s2 = 0.f, s3 = 0.f;
    for (int p = pg; p < NPART; p += 8) {
      uint2 u = *(const uint2*)(cp + (size_t)p * 16);
      s0 += bf_lo(u.x); s1 += bf_hi(u.x);
      s2 += bf_lo(u.y); s3 += bf_hi(u.y);
    }
    #pragma unroll
    for (int o = 8; o < 64; o <<= 1) {
      s0 += __shfl_xor(s0, o);
      s1 += __shfl_xor(s1, o);
      s2 += __shfl_xor(s2, o);
      s3 += __shfl_xor(s3, o);
    }
    if (pg == 0) {
      ctx_row[h * HD + c * 4]     = s0 * inv_l;
      ctx_row[h * HD + c * 4 + 1] = s1 * inv_l;
      ctx_row[h * HD + c * 4 + 2] = s2 * inv_l;
      ctx_row[h * HD + c * 4 + 3] = s3 * inv_l;
    }
  }
  __syncthreads();

  const int j = tid;
  float s = bo[j];
  const float4* wr = (const float4*)(Wo + (size_t)j * DM);
  #pragma unroll 8
  for (int c = 0; c < 64; ++c) {
    float4 wv = wr[c];
    float4 cx = ((const float4*)ctx_row)[c];
    s += wv.x * cx.x + wv.y * cx.y + wv.z * cx.z + wv.w * cx.w;
  }
  const float x = s + query[(size_t)bq * DM + j];

  float t = x;
  #pragma unroll
  for (int o = 1; o < 64; o <<= 1) t += __shfl_xor(t, o);
  if (lane == 0) red[wid] = t;
  __syncthreads();
  const float mu = (red[0] + red[1] + red[2] + red[3]) * (1.0f / DM);
  const float dx = x - mu;
  float t2 = dx * dx;
  #pragma unroll
  for (int o = 1; o < 64; o <<= 1) t2 += __shfl_xor(t2, o);
  if (lane == 0) red[4 + wid] = t2;
  __syncthreads();
  const float var = (red[4] + red[5] + red[6] + red[7]) * (1.0f / DM);
  out[(size_t)bq * DM + j] = dx * rsqrtf(var + 1e-5f) * lnw[j] + lnb[j];
}

// ---------------------------------------------------------------------------
extern "C" void kernel_launch(void* const* d_in, const int* in_sizes, int n_in,
                              void* d_out, int out_size, void* d_ws, size_t ws_size,
                              hipStream_t stream) {
  const float* query = (const float*)d_in[0];
  const float* kv    = (const float*)d_in[1];
  const int*   mask  = (const int*)d_in[2];
  const float* ipw   = (const float*)d_in[3];
  const float* ipb   = (const float*)d_in[4];
  const float* opw   = (const float*)d_in[5];
  const float* opb   = (const float*)d_in[6];
  const float* lnw   = (const float*)d_in[7];
  const float* lnb   = (const float*)d_in[8];
  float* out = (float*)d_out;

  char* ws = (char*)d_ws;
  // ws: k 64MiB | v_t 64MiB | q 0.5MiB | l_p 1.75MiB | ctxp 28.7MiB | wbf 0.25MiB | mbg 14MiB
  u16*   k_bf  = (u16*)(ws);
  u16*   v_t   = (u16*)(ws + 67108864);
  u16*   q_bf  = (u16*)(ws + 134217728);
  float* l_p   = (float*)(ws + 134742016);
  u32*   ctxp  = (u32*)(ws + 136577024);
  u16*   wbf   = (u16*)(ws + 195297280);
  u32*   mbg   = (u32*)(ws + 195559424);

  qw_kernel     <<<1024 + BB * QQ + 128, 256, 0, stream>>>(query, ipw, ipb, mask, q_bf, wbf, mbg);
  kv_kernel     <<<4096,                 512, 0, stream>>>(kv, wbf, ipb, k_bf, v_t);     // 2x diag
  attn_kernel   <<<2048,                 256, 0, stream>>>(q_bf, k_bf, v_t, mbg, l_p, ctxp); // 2x diag
  combine_kernel<<<BB * QQ,              256, 0, stream>>>(l_p, ctxp, query, opw, opb, lnw, lnb, out);
}

// Round 8
// 814.743 us; speedup vs baseline: 1.1678x; 1.1678x over previous
//
#include <hip/hip_runtime.h>
#include <stdint.h>

// Problem constants
#define BB   8
#define NH   8
#define QQ   100
#define HWK  16384
#define DM   256
#define HD   32
#define QP   112      // Q padded to 7 * 16
#define MT   7        // m-tiles of 16 rows
#define NPART 64      // key partials per (b,h): 16 chunks * 4 waves
// 1/sqrt(32) * log2(e)  (exp(x) == exp2(x*log2e), folded into q-scale)
#define SCALE2 0.2550602534365564f

// R8: budget established (R7 diag): kv+attn = 136us combined; qw ~ 150
// (mask ~135); combine ~35; fixed harness overhead (workspace poison fill
// 1.6GB + restores) ~ 485us inside the timed window. This round: mask
// compress 2-row unroll (128B/lane in flight, R1 lesson) + attn register
// double-buffer prefetch of next kg's K/V fragments.

typedef short bf16x8 __attribute__((ext_vector_type(8)));
typedef float f32x4  __attribute__((ext_vector_type(4)));
typedef unsigned short u16;
typedef unsigned int   u32;
typedef unsigned long long u64;

__device__ __forceinline__ u16 f2bf(float f) {          // RNE
  u32 u = __builtin_bit_cast(u32, f);
  u += 0x7fffu + ((u >> 16) & 1u);
  return (u16)(u >> 16);
}
__device__ __forceinline__ u16 f2bf_ru(float f) {       // round-half-up (2 VALU)
  return (u16)((__builtin_bit_cast(u32, f) + 0x8000u) >> 16);
}
// pack two fp32 -> bf16x2 (round-half-up), 3 VALU via v_perm
__device__ __forceinline__ u32 pack2rn(float lo, float hi) {
  u32 a = __builtin_bit_cast(u32, lo) + 0x8000u;
  u32 b = __builtin_bit_cast(u32, hi) + 0x8000u;
  return __builtin_amdgcn_perm(b, a, 0x07060302u);
}
__device__ __forceinline__ float bf_lo(u32 u) {
  return __builtin_bit_cast(float, u << 16);
}
__device__ __forceinline__ float bf_hi(u32 u) {
  return __builtin_bit_cast(float, u & 0xffff0000u);
}
__device__ __forceinline__ float fast_exp2(float x) {
#if __has_builtin(__builtin_amdgcn_exp2f)
  return __builtin_amdgcn_exp2f(x);
#else
  return exp2f(x);
#endif
}

// ---------------------------------------------------------------------------
// Kernel 1: mask ballot-compression (1024 blocks) + q projection (800) +
// wconv (128). Mask loop 2-row unrolled: 8 int4 loads (128B/lane) in flight
// before the ballot chain consumes them (R1: in-flight bytes is the lever).
// Bitmap format: per (bh,chunk,row): word = q*8 + h*4 + j (row stride 32),
// covering key q*256 + 4*(32h + bit) + j.
// ---------------------------------------------------------------------------
__global__ __launch_bounds__(256) void qw_kernel(
    const float* __restrict__ query, const float* __restrict__ W,
    const float* __restrict__ bias, const int* __restrict__ mask,
    u16* __restrict__ q_bf, u16* __restrict__ wbf, u32* __restrict__ mbg) {
  __shared__ float xrow[DM];
  const int bid = blockIdx.x;
  const int tid = threadIdx.x, lane = tid & 63, wid = tid >> 6;

  if (bid < 1024) {                           // ---- mask compress ----
    const int cpid = bid;                     // bh*16 + chunk
    const int bh = cpid >> 4, chunk = cpid & 15;
    const int* mp_base = mask + (size_t)bh * QQ * HWK + chunk * 1024;
    u32* dst_base = mbg + (size_t)cpid * QP * 32;
    const int row_base = wid * 25;
    #pragma unroll 1
    for (int rr = 0; rr < 24; rr += 2) {
      const int row0 = row_base + rr;
      const int* mp0 = mp_base + (size_t)row0 * HWK;
      const int* mp1 = mp0 + HWK;
      int4 v0[4], v1[4];
      #pragma unroll
      for (int q = 0; q < 4; ++q) v0[q] = ((const int4*)(mp0 + q * 256))[lane];
      #pragma unroll
      for (int q = 0; q < 4; ++q) v1[q] = ((const int4*)(mp1 + q * 256))[lane];
      #pragma unroll
      for (int q = 0; q < 4; ++q) {
        const u64 b0 = __ballot(v0[q].x != 0);
        const u64 b1 = __ballot(v0[q].y != 0);
        const u64 b2 = __ballot(v0[q].z != 0);
        const u64 b3 = __ballot(v0[q].w != 0);
        if (lane < 8) {
          const int j = lane >> 1;
          const u64 bj = (j == 0) ? b0 : (j == 1) ? b1 : (j == 2) ? b2 : b3;
          dst_base[row0 * 32 + q * 8 + (lane & 1) * 4 + j] =
              (lane & 1) ? (u32)(bj >> 32) : (u32)bj;
        }
      }
      #pragma unroll
      for (int q = 0; q < 4; ++q) {
        const u64 b0 = __ballot(v1[q].x != 0);
        const u64 b1 = __ballot(v1[q].y != 0);
        const u64 b2 = __ballot(v1[q].z != 0);
        const u64 b3 = __ballot(v1[q].w != 0);
        if (lane < 8) {
          const int j = lane >> 1;
          const u64 bj = (j == 0) ? b0 : (j == 1) ? b1 : (j == 2) ? b2 : b3;
          dst_base[(row0 + 1) * 32 + q * 8 + (lane & 1) * 4 + j] =
              (lane & 1) ? (u32)(bj >> 32) : (u32)bj;
        }
      }
    }
    {                                         // tail row (rr = 24)
      const int row = row_base + 24;
      const int* mp = mp_base + (size_t)row * HWK;
      int4 v[4];
      #pragma unroll
      for (int q = 0; q < 4; ++q) v[q] = ((const int4*)(mp + q * 256))[lane];
      #pragma unroll
      for (int q = 0; q < 4; ++q) {
        const u64 b0 = __ballot(v[q].x != 0);
        const u64 b1 = __ballot(v[q].y != 0);
        const u64 b2 = __ballot(v[q].z != 0);
        const u64 b3 = __ballot(v[q].w != 0);
        if (lane < 8) {
          const int j = lane >> 1;
          const u64 bj = (j == 0) ? b0 : (j == 1) ? b1 : (j == 2) ? b2 : b3;
          dst_base[row * 32 + q * 8 + (lane & 1) * 4 + j] =
              (lane & 1) ? (u32)(bj >> 32) : (u32)bj;
        }
      }
    }
    return;
  }
  if (bid >= 1024 + BB * QQ) {                // ---- wconv ----
    const int i = ((bid - 1024 - BB * QQ) * 256 + tid) * 4;  // 131072 elems
    const float4 w = *(const float4*)(W + 256 * DM + i);
    u32* dst = (u32*)(wbf + i);
    dst[0] = pack2rn(w.x, w.y);
    dst[1] = pack2rn(w.z, w.w);
    return;
  }
  // ---- q projection ----
  const int bq = bid - 1024;
  const int b = bq / QQ, qi = bq % QQ;
  if (tid < 64)
    ((float4*)xrow)[tid] = ((const float4*)(query + (size_t)bq * DM))[tid];
  __syncthreads();
  const int j = tid;
  float acc = bias[j];
  const float4* wr = (const float4*)(W + (size_t)j * DM);
  #pragma unroll 8
  for (int c = 0; c < 64; ++c) {
    float4 w = wr[c];
    float4 x = ((const float4*)xrow)[c];
    acc += w.x * x.x + w.y * x.y + w.z * x.z + w.w * x.w;
  }
  acc *= SCALE2;
  const int h = j >> 5, d = j & 31;
  q_bf[(((size_t)(b * NH + h)) * QQ + qi) * HD + d] = f2bf(acc);
}

// ---------------------------------------------------------------------------
// Kernel 2: K/V projection GEMM (R6 structure, unchanged).
// ---------------------------------------------------------------------------
__global__ __launch_bounds__(512, 4) void kv_kernel(
    const float* __restrict__ kv, const u16* __restrict__ wbf,
    const float* __restrict__ bias, u16* __restrict__ k_bf,
    u16* __restrict__ v_t) {
  __shared__ u16 S[19456];   // A [64][264] (16896 u16)  ∪  T: 4*2304 + 4*2560
  const int rb = blockIdx.x;                 // 2048 blocks of 64 keys
  const size_t m0 = (size_t)rb * 64;
  const int tid = threadIdx.x, lane = tid & 63, wid = tid >> 6;
  const int lane15 = lane & 15, quad = lane >> 4;
  const int jw = wid * 64;                   // col base within 512

  // ---- stage A (64 rows x 256 cols of kv) to LDS bf16, row stride 264 ----
  #pragma unroll
  for (int t = 0; t < 8; ++t) {
    const int idx = t * 512 + tid;           // float4 index, 4096 total
    const int row = idx >> 6, c4 = idx & 63;
    const float4 a = *(const float4*)(kv + (m0 + row) * DM + c4 * 4);
    u32* dst = (u32*)&S[row * 264 + c4 * 4];
    dst[0] = pack2rn(a.x, a.y);
    dst[1] = pack2rn(a.z, a.w);
  }
  __syncthreads();

  f32x4 acc[4][4];
  #pragma unroll
  for (int mi = 0; mi < 4; ++mi)
    #pragma unroll
    for (int ni = 0; ni < 4; ++ni) acc[mi][ni] = (f32x4){0.f, 0.f, 0.f, 0.f};

  for (int ks = 0; ks < 8; ++ks) {
    bf16x8 afr[4];
    #pragma unroll
    for (int mi = 0; mi < 4; ++mi)
      afr[mi] = __builtin_bit_cast(bf16x8,
          *(const uint4*)&S[(mi * 16 + lane15) * 264 + ks * 32 + quad * 8]);
    #pragma unroll
    for (int ni = 0; ni < 4; ++ni) {
      bf16x8 bfr = __builtin_bit_cast(bf16x8,
          *(const uint4*)(wbf + (size_t)(jw + ni * 16 + lane15) * DM + ks * 32 + quad * 8));
      #pragma unroll
      for (int mi = 0; mi < 4; ++mi)
        acc[mi][ni] = __builtin_amdgcn_mfma_f32_16x16x32_bf16(afr[mi], bfr, acc[mi][ni], 0, 0, 0);
    }
  }
  __syncthreads();   // all waves done reading A before T overwrites it

  const float* bptr = bias + 256 + jw;
  if (wid < 4) {
    u16* T = S + wid * 2304;                  // [32][72]
    #pragma unroll
    for (int p = 0; p < 2; ++p) {
      #pragma unroll
      for (int mm = 0; mm < 2; ++mm) {
        const int mi = p * 2 + mm;
        #pragma unroll
        for (int ni = 0; ni < 4; ++ni) {
          const float bv = bptr[ni * 16 + lane15];
          #pragma unroll
          for (int r = 0; r < 4; ++r)
            T[(mm * 16 + quad * 4 + r) * 72 + ni * 16 + lane15] =
                f2bf_ru(acc[mi][ni][r] + bv);
        }
      }
      #pragma unroll
      for (int it = 0; it < 8; ++it) {
        const int row = it * 4 + quad;          // 0..31
        const int c0 = lane15 * 4;              // 0..60
        uint2 val = *(const uint2*)&T[row * 72 + c0];
        const size_t m = m0 + p * 32 + row;
        const size_t b = m >> 14, key = m & 16383;
        const int col256 = jw + c0;             // 0..255 within K
        const int h = col256 >> 5, d = col256 & 31;
        *(uint2*)&k_bf[((b * NH + h) * HWK + key) * HD + d] = val;
      }
    }
  } else {
    u16* T = S + 9216 + (wid - 4) * 2560;     // [64][40]
    const int jwv = jw - 256;                  // 0..192 within V
    #pragma unroll
    for (int p = 0; p < 2; ++p) {
      #pragma unroll
      for (int mm = 0; mm < 2; ++mm) {
        const int mi = p * 2 + mm;
        #pragma unroll
        for (int ni = 0; ni < 4; ++ni) {
          const float bv = bptr[ni * 16 + lane15];
          u32* dst = (u32*)&T[(ni * 16 + lane15) * 40 + mm * 16 + quad * 4];
          dst[0] = pack2rn(acc[mi][ni][0] + bv, acc[mi][ni][1] + bv);
          dst[1] = pack2rn(acc[mi][ni][2] + bv, acc[mi][ni][3] + bv);
        }
      }
      #pragma unroll
      for (int it = 0; it < 4; ++it) {
        const int col = it * 16 + (lane >> 2);  // 0..63
        const int koff = (lane & 3) * 8;        // 0..24
        uint4 val = *(const uint4*)&T[col * 40 + koff];
        const size_t m = m0 + p * 32 + koff;
        const size_t b = m >> 14, key = m & 16383;
        const int col256 = jwv + col;           // 0..255 within V
        const int h = col256 >> 5, d = col256 & 31;
        *(uint4*)&v_t[((b * NH + h) * HD + d) * HWK + key] = val;
      }
    }
  }
}

// ---------------------------------------------------------------------------
// Kernel 3: attention, shuffle-free P path + register double-buffer of the
// next kg's K/V fragments (64B/lane prefetched under the current kg's 28
// MFMAs -> load latency hidden across kg iterations).
// ---------------------------------------------------------------------------
__global__ __launch_bounds__(256) void attn_kernel(
    const u16* __restrict__ q_bf, const u16* __restrict__ k_bf,
    const u16* __restrict__ v_t, const u32* __restrict__ mbg,
    float* __restrict__ l_p, u32* __restrict__ ctxp) {
  const int tid = threadIdx.x;
  const int lane = tid & 63, wid = tid >> 6;
  const int lane15 = lane & 15, quad = lane >> 4;
  const int bh = blockIdx.x >> 4, chunk = blockIdx.x & 15;

  const int key_base = chunk * 1024 + wid * 256;
  const u16* kbase = k_bf + (size_t)bh * HWK * HD;
  const u16* vtb  = v_t  + (size_t)bh * HWK * HD;
  const u16* qb   = q_bf + (size_t)bh * QQ * HD;
  const u32* mrow = mbg + (size_t)blockIdx.x * QP * 32 + wid * 8;

  // permuted key offset for this lane's A-rows: row l15 <- key kp (kf0), kp+4 (kf1)
  const int kp = 8 * (lane15 >> 2) + (lane15 & 3);

#define LOAD_KV(kgx, K0, K1, V0, V1)                                          \
  {                                                                           \
    const int key0_ = key_base + (kgx) * 32;                                  \
    K0 = __builtin_bit_cast(bf16x8,                                           \
        *(const uint4*)(kbase + (size_t)(key0_ + kp) * HD + quad * 8));       \
    K1 = __builtin_bit_cast(bf16x8,                                           \
        *(const uint4*)(kbase + (size_t)(key0_ + kp + 4) * HD + quad * 8));   \
    V0 = __builtin_bit_cast(bf16x8,                                           \
        *(const uint4*)(vtb + (size_t)lane15 * HWK + key0_ + quad * 8));      \
    V1 = __builtin_bit_cast(bf16x8,                                           \
        *(const uint4*)(vtb + (size_t)(lane15 + 16) * HWK + key0_ + quad * 8)); \
  }

  f32x4 acc[MT][2];
  float l_run[MT];
  #pragma unroll
  for (int mt = 0; mt < MT; ++mt) {
    acc[mt][0] = (f32x4){0.f, 0.f, 0.f, 0.f};
    acc[mt][1] = (f32x4){0.f, 0.f, 0.f, 0.f};
    l_run[mt] = 0.f;
  }

  bf16x8 kf0c, kf1c, vf0c, vf1c;
  LOAD_KV(0, kf0c, kf1c, vf0c, vf1c);

  for (int kg = 0; kg < 8; ++kg) {
    bf16x8 kf0n, kf1n, vf0n, vf1n;
    if (kg < 7) LOAD_KV(kg + 1, kf0n, kf1n, vf0n, vf1n);
    const int h4 = (kg & 4) ? 4 : 0;
    const int sh = ((kg & 3) << 3) + 2 * quad;        // bit base for this kg
    #pragma unroll
    for (int mt = 0; mt < MT; ++mt) {
      const int rowg = mt * 16 + lane15;              // this lane's q-row
      bf16x8 af = __builtin_bit_cast(bf16x8,
          *(const uint4*)(qb + (size_t)rowg * HD + quad * 8));
      uint4 mwv = *(const uint4*)(mrow + rowg * 32 + h4); // words j=0..3
      if (mt == MT - 1 && rowg >= QQ) mwv = (uint4){0u, 0u, 0u, 0u};
      const f32x4 zero = {0.f, 0.f, 0.f, 0.f};
      // S^T: lane (q,l15) rows 4q+r -> keys key0 + {8q+r (s0), 8q+4+r (s1)}
      f32x4 s0 = __builtin_amdgcn_mfma_f32_16x16x32_bf16(kf0c, af, zero, 0, 0, 0);
      f32x4 s1 = __builtin_amdgcn_mfma_f32_16x16x32_bf16(kf1c, af, zero, 0, 0, 0);
      const u32 mw[4] = {mwv.x, mwv.y, mwv.z, mwv.w};
      float p0[4], p1[4];
      float lsum = 0.f;
      #pragma unroll
      for (int r = 0; r < 4; ++r) {
        // key 8q+r   -> word r, bit sh; key 8q+4+r -> word r, bit sh+1
        p0[r] = ((mw[r] >> sh) & 1u)       ? fast_exp2(s0[r]) : 0.f;
        p1[r] = ((mw[r] >> (sh + 1)) & 1u) ? fast_exp2(s1[r]) : 0.f;
        lsum += p0[r] + p1[r];
      }
      l_run[mt] += lsum;
      // PV B-fragment: elems j=0..7 = P[key 8q+j] = {p0[0..3], p1[0..3]}
      uint4 pw;
      pw.x = pack2rn(p0[0], p0[1]);
      pw.y = pack2rn(p0[2], p0[3]);
      pw.z = pack2rn(p1[0], p1[1]);
      pw.w = pack2rn(p1[2], p1[3]);
      bf16x8 pf = __builtin_bit_cast(bf16x8, pw);
      // ctx^T: m=dim, n=qrow
      acc[mt][0] = __builtin_amdgcn_mfma_f32_16x16x32_bf16(vf0c, pf, acc[mt][0], 0, 0, 0);
      acc[mt][1] = __builtin_amdgcn_mfma_f32_16x16x32_bf16(vf1c, pf, acc[mt][1], 0, 0, 0);
    }
    kf0c = kf0n; kf1c = kf1n; vf0c = vf0n; vf1c = vf1n;
  }
#undef LOAD_KV

  const int part = chunk * 4 + wid;
  #pragma unroll
  for (int mt = 0; mt < MT; ++mt) {
    const int row = mt * 16 + lane15;               // qrow (rows >= 100 junk, never read)
    float lr = l_run[mt];
    lr += __shfl_xor(lr, 16);
    lr += __shfl_xor(lr, 32);
    const size_t base = ((size_t)bh * QP + row) * NPART + part;
    if (quad == 0) l_p[base] = lr;
    // ctx^T: lane holds dims quad*4+r (acc0) and 16+quad*4+r (acc1), qrow=lane15
    uint2 lo2, hi2;
    lo2.x = pack2rn(acc[mt][0][0], acc[mt][0][1]);
    lo2.y = pack2rn(acc[mt][0][2], acc[mt][0][3]);
    hi2.x = pack2rn(acc[mt][1][0], acc[mt][1][1]);
    hi2.y = pack2rn(acc[mt][1][2], acc[mt][1][3]);
    *(uint2*)&ctxp[base * 16 + quad * 2]     = lo2;  // dims 4q..4q+3
    *(uint2*)&ctxp[base * 16 + 8 + quad * 2] = hi2;  // dims 16+4q..16+4q+3
  }
}

// ---------------------------------------------------------------------------
// Kernel 4: combine partials (bf16-packed ctx) + out-proj + residual + LN.
// (Unchanged.)
// ---------------------------------------------------------------------------
__global__ __launch_bounds__(256) void combine_kernel(
    const float* __restrict__ l_p, const u32* __restrict__ ctxp,
    const float* __restrict__ query, const float* __restrict__ Wo,
    const float* __restrict__ bo, const float* __restrict__ lnw,
    const float* __restrict__ lnb, float* __restrict__ out) {
  __shared__ float ctx_row[DM];
  __shared__ float red[8];
  const int bq = blockIdx.x;
  const int b = bq / QQ, qi = bq % QQ;
  const int tid = threadIdx.x, lane = tid & 63, wid = tid >> 6;

  for (int hh = 0; hh < 2; ++hh) {
    const int h = wid * 2 + hh;
    const size_t base = ((size_t)(b * NH + h) * QP + qi) * NPART;
    float lv = l_p[base + lane];
    #pragma unroll
    for (int o = 1; o < 64; o <<= 1) lv += __shfl_xor(lv, o);
    const float inv_l = 1.0f / lv;
    // lane = (part group pg, u32-pair c): dims 4c..4c+3
    const int c = lane & 7, pg = lane >> 3;
    const u32* cp = ctxp + base * 16 + c * 2;
    float s0 = 0.f, s1 = 0.f, s2 = 0.f, s3 = 0.f;
    for (int p = pg; p < NPART; p += 8) {
      uint2 u = *(const uint2*)(cp + (size_t)p * 16);
      s0 += bf_lo(u.x); s1 += bf_hi(u.x);
      s2 += bf_lo(u.y); s3 += bf_hi(u.y);
    }
    #pragma unroll
    for (int o = 8; o < 64; o <<= 1) {
      s0 += __shfl_xor(s0, o);
      s1 += __shfl_xor(s1, o);
      s2 += __shfl_xor(s2, o);
      s3 += __shfl_xor(s3, o);
    }
    if (pg == 0) {
      ctx_row[h * HD + c * 4]     = s0 * inv_l;
      ctx_row[h * HD + c * 4 + 1] = s1 * inv_l;
      ctx_row[h * HD + c * 4 + 2] = s2 * inv_l;
      ctx_row[h * HD + c * 4 + 3] = s3 * inv_l;
    }
  }
  __syncthreads();

  const int j = tid;
  float s = bo[j];
  const float4* wr = (const float4*)(Wo + (size_t)j * DM);
  #pragma unroll 8
  for (int c = 0; c < 64; ++c) {
    float4 wv = wr[c];
    float4 cx = ((const float4*)ctx_row)[c];
    s += wv.x * cx.x + wv.y * cx.y + wv.z * cx.z + wv.w * cx.w;
  }
  const float x = s + query[(size_t)bq * DM + j];

  float t = x;
  #pragma unroll
  for (int o = 1; o < 64; o <<= 1) t += __shfl_xor(t, o);
  if (lane == 0) red[wid] = t;
  __syncthreads();
  const float mu = (red[0] + red[1] + red[2] + red[3]) * (1.0f / DM);
  const float dx = x - mu;
  float t2 = dx * dx;
  #pragma unroll
  for (int o = 1; o < 64; o <<= 1) t2 += __shfl_xor(t2, o);
  if (lane == 0) red[4 + wid] = t2;
  __syncthreads();
  const float var = (red[4] + red[5] + red[6] + red[7]) * (1.0f / DM);
  out[(size_t)bq * DM + j] = dx * rsqrtf(var + 1e-5f) * lnw[j] + lnb[j];
}

// ---------------------------------------------------------------------------
extern "C" void kernel_launch(void* const* d_in, const int* in_sizes, int n_in,
                              void* d_out, int out_size, void* d_ws, size_t ws_size,
                              hipStream_t stream) {
  const float* query = (const float*)d_in[0];
  const float* kv    = (const float*)d_in[1];
  const int*   mask  = (const int*)d_in[2];
  const float* ipw   = (const float*)d_in[3];
  const float* ipb   = (const float*)d_in[4];
  const float* opw   = (const float*)d_in[5];
  const float* opb   = (const float*)d_in[6];
  const float* lnw   = (const float*)d_in[7];
  const float* lnb   = (const float*)d_in[8];
  float* out = (float*)d_out;

  char* ws = (char*)d_ws;
  // ws: k 64MiB | v_t 64MiB | q 0.5MiB | l_p 1.75MiB | ctxp 28.7MiB | wbf 0.25MiB | mbg 14MiB
  u16*   k_bf  = (u16*)(ws);
  u16*   v_t   = (u16*)(ws + 67108864);
  u16*   q_bf  = (u16*)(ws + 134217728);
  float* l_p   = (float*)(ws + 134742016);
  u32*   ctxp  = (u32*)(ws + 136577024);
  u16*   wbf   = (u16*)(ws + 195297280);
  u32*   mbg   = (u32*)(ws + 195559424);

  qw_kernel     <<<1024 + BB * QQ + 128, 256, 0, stream>>>(query, ipw, ipb, mask, q_bf, wbf, mbg);
  kv_kernel     <<<2048,                 512, 0, stream>>>(kv, wbf, ipb, k_bf, v_t);
  attn_kernel   <<<BB * NH * 16,         256, 0, stream>>>(q_bf, k_bf, v_t, mbg, l_p, ctxp);
  combine_kernel<<<BB * QQ,              256, 0, stream>>>(l_p, ctxp, query, opw, opb, lnw, lnb, out);
}